// Round 8
// baseline (293.744 us; speedup 1.0000x reference)
//
#include <hip/hip_runtime.h>

typedef int   i32x8 __attribute__((ext_vector_type(8)));
typedef float f32x4 __attribute__((ext_vector_type(4)));

#define D_DIM 256
#define LOG2E 1.4426950408889634f
#define LN2   0.6931471805599453f

#if __has_builtin(__builtin_amdgcn_exp2f)
static __device__ __forceinline__ float exp2_fast(float x) { return __builtin_amdgcn_exp2f(x); }
#else
static __device__ __forceinline__ float exp2_fast(float x) { return __expf(x * LN2); }
#endif
#if __has_builtin(__builtin_amdgcn_logf)
static __device__ __forceinline__ float log2_fast(float x) { return __builtin_amdgcn_logf(x); }
#else
static __device__ __forceinline__ float log2_fast(float x) { return __logf(x) * LOG2E; }
#endif

// ---- fp32 -> fp8 e4m3 (OCP on gfx950) packing, 4 at a time -----------------
#if __has_builtin(__builtin_amdgcn_cvt_pk_fp8_f32)
static __device__ __forceinline__ unsigned int pack4_fp8(float a, float b, float c, float d) {
    int v = 0;
    v = __builtin_amdgcn_cvt_pk_fp8_f32(a, b, v, false);   // bytes 0,1
    v = __builtin_amdgcn_cvt_pk_fp8_f32(c, d, v, true);    // bytes 2,3
    return (unsigned int)v;
}
#else
#include <hip/hip_fp8.h>
static __device__ __forceinline__ unsigned char cv1(float x) {
    __hip_fp8_e4m3 f(x);
    union { __hip_fp8_e4m3 f; unsigned char b; } u; u.f = f; return u.b;
}
static __device__ __forceinline__ unsigned int pack4_fp8(float a, float b, float c, float d) {
    return (unsigned int)cv1(a) | ((unsigned int)cv1(b) << 8) |
           ((unsigned int)cv1(c) << 16) | ((unsigned int)cv1(d) << 24);
}
#endif

// ---- K=128 fp8 MFMA: MX-scaled if available (2x rate), else 4x K=32 --------
static __device__ __forceinline__ f32x4 mfma_fp8_k128(i32x8 a, i32x8 b, f32x4 c) {
#if __has_builtin(__builtin_amdgcn_mfma_scale_f32_16x16x128_f8f6f4)
    // cbsz=0/blgp=0 -> fp8 e4m3 for A and B; scales = E8M0 127 = 1.0, opsel byte 0.
    return __builtin_amdgcn_mfma_scale_f32_16x16x128_f8f6f4(a, b, c, 0, 0, 0, 127, 0, 127);
#else
    // Fallback: 4 chained K=32 fp8 MFMAs over the same 32-byte fragments.
    // A/B use identical k-permutations, so any layout guess cancels in A.B^T.
    union { i32x8 v; long l[4]; } ua, ub;
    ua.v = a; ub.v = b;
#pragma unroll
    for (int s = 0; s < 4; ++s)
        c = __builtin_amdgcn_mfma_f32_16x16x32_fp8_fp8(ua.l[s], ub.l[s], c, 0, 0, 0);
    return c;
#endif
}

// Kernel 1: row L2-normalize fp32 -> fp8 e4m3 (plain normalized; the exp(t')
// scale is applied in the epilogue fma, costing nothing). Zeroes out[0].
__global__ __launch_bounds__(256) void norm_cast_kernel(
    const float* __restrict__ img, const float* __restrict__ txt,
    unsigned char* __restrict__ Ab, unsigned char* __restrict__ Bb,
    float* __restrict__ out, int N)
{
    int wave = threadIdx.x >> 6;
    int lane = threadIdx.x & 63;
    int row  = blockIdx.x * 4 + wave;      // 0..2N-1

    const float* src;
    unsigned char* dst;
    if (row < N) {
        src = img + (size_t)row * D_DIM;
        dst = Ab  + (size_t)row * D_DIM;
    } else {
        src = txt + (size_t)(row - N) * D_DIM;
        dst = Bb  + (size_t)(row - N) * D_DIM;
    }

    float4 v = ((const float4*)src)[lane];
    float ss = v.x * v.x + v.y * v.y + v.z * v.z + v.w * v.w;
#pragma unroll
    for (int off = 32; off > 0; off >>= 1)
        ss += __shfl_xor(ss, off, 64);

    float inv = 1.0f / fmaxf(sqrtf(ss), 1e-12f);

    *(unsigned int*)(dst + lane * 4) =
        pack4_fp8(v.x * inv, v.y * inv, v.z * inv, v.w * inv);

    if (blockIdx.x == 0 && threadIdx.x == 0) out[0] = 0.0f;
}

// Kernel 2: fused fp8 Gram + softplus-sum + inline diagonal correction.
//  Block = 256 thr (4 waves, 2x2), tile 128x128; wave tile 64x64 = 4x4 of
//  16x16x128 MX-fp8 MFMA (K = 256 = 2 chunks). Whole A/B strips (2x16 KB
//  each) staged ONCE via global_load_lds -> ONE barrier per block.
//  LDS: 128-B rows; lane's 32-B fragment read at pair-index
//  quad ^ ((m16>>1)&3) -> exactly 2 lanes per 8-bank group (free).
//  Staging permutes 32-B pairs within each 128-B row to match.
//  64 KB LDS + ~150 regs -> 2 desynced blocks/CU.
__global__ __launch_bounds__(256, 2) void siglip_loss_kernel(
    const unsigned char* __restrict__ A, const unsigned char* __restrict__ B,
    const float* __restrict__ t_prime, const float* __restrict__ bias,
    float* __restrict__ out, int N)
{
    __shared__ unsigned char As[2][128 * 128];   // [k-chunk][row*128 + byte]
    __shared__ unsigned char Bs[2][128 * 128];
    __shared__ float red[4];

    const int tid  = threadIdx.x;
    const int wave = tid >> 6;
    const int lane = tid & 63;
    const int m16  = lane & 15;
    const int quad = lane >> 4;       // 0..3
    const int wv   = wave >> 1;       // 0..1
    const int wu   = wave & 1;        // 0..1

    // 16x16 supertile block swizzle for L2 locality (grid = 16384, 1-D).
    const int bid = blockIdx.x;
    const int st  = bid >> 8;         // 0..63 supertiles (8x8)
    const int l2  = bid & 255;        // 16x16 within
    const int bx  = (st & 7) * 16 + (l2 & 15);
    const int by  = (st >> 3) * 16 + (l2 >> 4);
    const int rowBase = by * 128;
    const int colBase = bx * 128;

    const unsigned char* Ag = A + (size_t)rowBase * D_DIM;
    const unsigned char* Bg = B + (size_t)colBase * D_DIM;

    // Staging: lane l writes LDS bytes [l*16, l*16+16) of a 1 KB (8-row)
    // region. LDS 16B-chunk index c16 = l&7, row r = r0 + (l>>3). Source
    // global 32-B pair is XOR-swizzled: pair_src = (c16>>1) ^ ((r>>1)&3).
    const int st_r  = lane >> 3;
    const int st_c  = lane & 7;
    auto stage = [&](const unsigned char* G, unsigned char (&S)[2][128 * 128]) {
#pragma unroll
        for (int kk = 0; kk < 2; ++kk)
#pragma unroll
            for (int c = 0; c < 4; ++c) {
                int r0 = wave * 32 + c * 8;
                int r  = r0 + st_r;
                int src = (((st_c >> 1) ^ ((r >> 1) & 3)) * 32) + (st_c & 1) * 16;
                const unsigned char* gp = G + (size_t)r * D_DIM + kk * 128 + src;
                __builtin_amdgcn_global_load_lds(
                    (const __attribute__((address_space(1))) unsigned int*)gp,
                    (__attribute__((address_space(3))) unsigned int*)&S[kk][r0 * 128],
                    16, 0, 0);
            }
    };
    stage(Ag, As);
    stage(Bg, Bs);

    // fragment read offsets: row lr, 32 B at pair (quad ^ ((m16>>1)&3))*32
    const int pswz = (quad ^ ((m16 >> 1) & 3)) * 32;
    int a_off[4], b_off[4];
#pragma unroll
    for (int i = 0; i < 4; ++i) {
        a_off[i] = (wv * 64 + i * 16 + m16) * 128 + pswz;
        b_off[i] = (wu * 64 + i * 16 + m16) * 128 + pswz;
    }

    __syncthreads();                  // the ONLY barrier before reduction

    f32x4 acc[4][4] = {};
#pragma unroll
    for (int kk = 0; kk < 2; ++kk) {
        i32x8 av[4], bv[4];
#pragma unroll
        for (int i = 0; i < 4; ++i) {
            av[i] = *(const i32x8*)&As[kk][a_off[i]];
            bv[i] = *(const i32x8*)&Bs[kk][b_off[i]];
        }
#pragma unroll
        for (int i = 0; i < 4; ++i)
#pragma unroll
            for (int j = 0; j < 4; ++j)
                acc[i][j] = mfma_fp8_k128(av[i], bv[j], acc[i][j]);
    }

    // Epilogue: z2 = s2*acc + b2 (log2 domain); sum log2 of products of 8.
    const float s2 = __expf(t_prime[0]) * LOG2E;
    const float b2 = bias[0] * LOG2E;
    float local = 0.0f;
#pragma unroll
    for (int i = 0; i < 4; ++i)
#pragma unroll
        for (int jp = 0; jp < 2; ++jp) {
            float x[8];
#pragma unroll
            for (int jj = 0; jj < 2; ++jj)
#pragma unroll
                for (int r = 0; r < 4; ++r)
                    x[jj * 4 + r] = exp2_fast(fmaf(s2, acc[i][jp * 2 + jj][r], b2));
            float p = 1.0f + x[0];
#pragma unroll
            for (int e = 1; e < 8; ++e)
                p = fmaf(p, x[e], p);          // p *= (1 + x[e])
            local += log2_fast(p);
        }

    // Diagonal blocks (128 of 16384): softplus(-z) = softplus(z) - z.
    if (rowBase == colBase) {
#pragma unroll
        for (int i = 0; i < 4; ++i)
#pragma unroll
            for (int j = 0; j < 4; ++j)
#pragma unroll
                for (int r = 0; r < 4; ++r) {
                    // C/D layout (16x16, shape-determined): col=m16, row=quad*4+r
                    int grow = wv * 64 + i * 16 + quad * 4 + r;
                    int gcol = wu * 64 + j * 16 + m16;
                    if (grow == gcol) local -= fmaf(s2, acc[i][j][r], b2);
                }
    }

#pragma unroll
    for (int off = 32; off > 0; off >>= 1)
        local += __shfl_xor(local, off, 64);
    if (lane == 0) red[wave] = local;
    __syncthreads();
    if (tid == 0) {
        float total = (red[0] + red[1]) + (red[2] + red[3]);
        atomicAdd(out, total * (LN2 / (float)N));
    }
}

extern "C" void kernel_launch(void* const* d_in, const int* in_sizes, int n_in,
                              void* d_out, int out_size, void* d_ws, size_t ws_size,
                              hipStream_t stream) {
    const float* img = (const float*)d_in[0];
    const float* txt = (const float*)d_in[1];
    const float* tp  = (const float*)d_in[2];
    const float* bs  = (const float*)d_in[3];
    float* out = (float*)d_out;
    int N = in_sizes[0] / D_DIM;    // 16384

    unsigned char* Ab = (unsigned char*)d_ws;       // N*256 fp8 = 4 MB
    unsigned char* Bb = Ab + (size_t)N * D_DIM;     // +4 MB

    norm_cast_kernel<<<(2 * N) / 4, 256, 0, stream>>>(img, txt, Ab, Bb, out, N);

    int nblk = (N / 128) * (N / 128);               // 16384
    siglip_loss_kernel<<<nblk, 256, 0, stream>>>(Ab, Bb, tp, bs, out, N);
}

// Round 9
// 293.032 us; speedup vs baseline: 1.0024x; 1.0024x over previous
//
#include <hip/hip_runtime.h>

typedef int   i32x4 __attribute__((ext_vector_type(4)));
typedef int   i32x8 __attribute__((ext_vector_type(8)));
typedef float f32x16 __attribute__((ext_vector_type(16)));

#define D_DIM 256
#define LOG2E 1.4426950408889634f
#define LN2   0.6931471805599453f
// Transposed workspace layout: [strip of 128 rows][kc16 0..15][row 0..127][16B]
#define STRIP_BYTES 32768

#if __has_builtin(__builtin_amdgcn_exp2f)
static __device__ __forceinline__ float exp2_fast(float x) { return __builtin_amdgcn_exp2f(x); }
#else
static __device__ __forceinline__ float exp2_fast(float x) { return __expf(x * LN2); }
#endif
#if __has_builtin(__builtin_amdgcn_logf)
static __device__ __forceinline__ float log2_fast(float x) { return __builtin_amdgcn_logf(x); }
#else
static __device__ __forceinline__ float log2_fast(float x) { return __logf(x) * LOG2E; }
#endif

#if __has_builtin(__builtin_amdgcn_cvt_pk_fp8_f32)
static __device__ __forceinline__ unsigned int pack4_fp8(float a, float b, float c, float d) {
    int v = 0;
    v = __builtin_amdgcn_cvt_pk_fp8_f32(a, b, v, false);
    v = __builtin_amdgcn_cvt_pk_fp8_f32(c, d, v, true);
    return (unsigned int)v;
}
#else
#include <hip/hip_fp8.h>
static __device__ __forceinline__ unsigned char cv1(float x) {
    __hip_fp8_e4m3 f(x);
    union { __hip_fp8_e4m3 f; unsigned char b; } u; u.f = f; return u.b;
}
static __device__ __forceinline__ unsigned int pack4_fp8(float a, float b, float c, float d) {
    return (unsigned int)cv1(a) | ((unsigned int)cv1(b) << 8) |
           ((unsigned int)cv1(c) << 16) | ((unsigned int)cv1(d) << 24);
}
#endif

// K=64 fp8 MFMA (32x32): MX-scaled if available, else 4x K=16 non-scaled.
static __device__ __forceinline__ f32x16 mfma_fp8_32x32_k64(i32x8 a, i32x8 b, f32x16 c) {
#if __has_builtin(__builtin_amdgcn_mfma_scale_f32_32x32x64_f8f6f4)
    return __builtin_amdgcn_mfma_scale_f32_32x32x64_f8f6f4(a, b, c, 0, 0, 0, 127, 0, 127);
#else
    union { i32x8 v; long l[4]; } ua, ub;
    ua.v = a; ub.v = b;
#pragma unroll
    for (int s = 0; s < 4; ++s)
        c = __builtin_amdgcn_mfma_f32_32x32x16_fp8_fp8(ua.l[s], ub.l[s], c, 0, 0, 0);
    return c;
#endif
}

// Kernel 1: L2-normalize fp32 -> fp8 e4m3, writing the k-major strip layout:
// byte(row, k) -> strip(row>>7)*32768 + (k>>4)*2048 + (row&127)*16 + (k&15).
// Block = 256 thr <-> 64 rows; thread (row rl, quarter q) owns 64 floats.
__global__ __launch_bounds__(256) void norm_cast_kernel(
    const float* __restrict__ img, const float* __restrict__ txt,
    unsigned char* __restrict__ Ab, unsigned char* __restrict__ Bb,
    float* __restrict__ out, int N)
{
    const int tid = threadIdx.x;
    const int q   = tid & 3;          // k-quarter (64 floats)
    const int rl  = tid >> 2;         // 0..63
    int gRow = blockIdx.x * 64 + rl;  // 0..2N-1

    const float* src;
    unsigned char* dstB;
    int row;
    if (gRow < N) { row = gRow;     src = img + (size_t)row * D_DIM; dstB = Ab; }
    else          { row = gRow - N; src = txt + (size_t)row * D_DIM; dstB = Bb; }

    float f[64];
    float ss = 0.0f;
    const float4* s4 = (const float4*)(src + q * 64);
#pragma unroll
    for (int i = 0; i < 16; ++i) {
        float4 v = s4[i];
        f[4*i+0] = v.x; f[4*i+1] = v.y; f[4*i+2] = v.z; f[4*i+3] = v.w;
        ss += v.x*v.x + v.y*v.y + v.z*v.z + v.w*v.w;
    }
    // 4 lanes per row (consecutive): xor-1 and xor-2 reduce within the quad.
    ss += __shfl_xor(ss, 1, 64);
    ss += __shfl_xor(ss, 2, 64);
    float inv = 1.0f / fmaxf(sqrtf(ss), 1e-12f);   // F.normalize eps

    unsigned char* dst = dstB + (size_t)(row >> 7) * STRIP_BYTES + (row & 127) * 16;
#pragma unroll
    for (int g = 0; g < 4; ++g) {
        const float* h = f + g * 16;
        uint4 w;
        w.x = pack4_fp8(h[ 0]*inv, h[ 1]*inv, h[ 2]*inv, h[ 3]*inv);
        w.y = pack4_fp8(h[ 4]*inv, h[ 5]*inv, h[ 6]*inv, h[ 7]*inv);
        w.z = pack4_fp8(h[ 8]*inv, h[ 9]*inv, h[10]*inv, h[11]*inv);
        w.w = pack4_fp8(h[12]*inv, h[13]*inv, h[14]*inv, h[15]*inv);
        *(uint4*)(dst + (q * 4 + g) * 2048) = w;   // 16-B aligned, kc = q*4+g
    }

    if (blockIdx.x == 0 && tid == 0) out[0] = 0.0f;
}

// Kernel 2: fp8-MX Gram + softplus-sum + inline diag.
//  Tile 128x128, 4 waves (2x2), wave 64x64 = 2x2 of 32x32x64 MX MFMA.
//  K = 256 as 4 chunks of 64; LDS = dbuf (A 8KB + B 8KB) x2 = 32 KB
//  -> 4 blocks/CU at <=128 VGPR (launch_bounds(256,4)) = 4 waves/SIMD.
//  Staging: strips are verbatim k-major -> 1-KB contiguous global_load_lds.
//  Fragment reads: addr = (kc*128 + row)*16; 8 consecutive lanes cover 128
//  contiguous bytes = all 32 banks once -> conflict-free by construction.
__global__ __launch_bounds__(256, 4) void siglip_loss_kernel(
    const unsigned char* __restrict__ A, const unsigned char* __restrict__ B,
    const float* __restrict__ t_prime, const float* __restrict__ bias,
    float* __restrict__ out, int N)
{
    __shared__ unsigned char As[2][8192];   // [kc16 0..3][row 0..127][16B]
    __shared__ unsigned char Bs[2][8192];
    __shared__ float red[4];

    const int tid  = threadIdx.x;
    const int wave = tid >> 6;
    const int lane = tid & 63;
    const int r31  = lane & 31;
    const int g    = lane >> 5;       // k-group (2 kc16 chunks of the 4)
    const int wv   = wave >> 1;       // 0..1 row half
    const int wu   = wave & 1;        // 0..1 col half

    // 16x16 supertile swizzle for L2 locality (grid 16384 flat).
    const int bid = blockIdx.x;
    const int st  = bid >> 8;
    const int l2  = bid & 255;
    const int bx  = (st & 7) * 16 + (l2 & 15);
    const int by  = (st >> 3) * 16 + (l2 >> 4);
    const int rowBase = by * 128;
    const int colBase = bx * 128;

    const unsigned char* Astrip = A + (size_t)by * STRIP_BYTES;
    const unsigned char* Bstrip = B + (size_t)bx * STRIP_BYTES;

    // Stage K-chunk c (8 KB per operand = 8 x 1KB loads, 2 per wave each).
    auto stage = [&](int buf, int c) {
        const unsigned char* ga = Astrip + c * 8192;
        const unsigned char* gb = Bstrip + c * 8192;
#pragma unroll
        for (int l = 0; l < 2; ++l) {
            int idx = wave * 2 + l;   // 0..7
            __builtin_amdgcn_global_load_lds(
                (const __attribute__((address_space(1))) unsigned int*)(ga + idx * 1024 + lane * 16),
                (__attribute__((address_space(3))) unsigned int*)&As[buf][idx * 1024],
                16, 0, 0);
            __builtin_amdgcn_global_load_lds(
                (const __attribute__((address_space(1))) unsigned int*)(gb + idx * 1024 + lane * 16),
                (__attribute__((address_space(3))) unsigned int*)&Bs[buf][idx * 1024],
                16, 0, 0);
        }
    };

    stage(0, 0);

    // Fragment LDS offsets: kc_local = 2g (+1 for the second 16B half).
    int a_off[2], b_off[2];
#pragma unroll
    for (int i = 0; i < 2; ++i) a_off[i] = g * 4096 + (wv * 64 + i * 32 + r31) * 16;
#pragma unroll
    for (int j = 0; j < 2; ++j) b_off[j] = g * 4096 + (wu * 64 + j * 32 + r31) * 16;

    f32x16 acc[2][2] = {};
    union F { i32x8 v8; i32x4 v4[2]; };

#pragma unroll 1
    for (int c = 0; c < 4; ++c) {
        __syncthreads();                    // publishes buffer c&1
        if (c < 3) stage((c + 1) & 1, c + 1);

        const unsigned char* as = As[c & 1];
        const unsigned char* bs = Bs[c & 1];
        F a[2], b[2];
#pragma unroll
        for (int i = 0; i < 2; ++i) {
            a[i].v4[0] = *(const i32x4*)&as[a_off[i]];
            a[i].v4[1] = *(const i32x4*)&as[a_off[i] + 2048];
            b[i].v4[0] = *(const i32x4*)&bs[b_off[i]];
            b[i].v4[1] = *(const i32x4*)&bs[b_off[i] + 2048];
        }
#pragma unroll
        for (int i = 0; i < 2; ++i)
#pragma unroll
            for (int j = 0; j < 2; ++j)
                acc[i][j] = mfma_fp8_32x32_k64(a[i].v8, b[j].v8, acc[i][j]);
    }

    // Epilogue: z2 = s2*acc + b2 (log2 domain); log2 of products of 8.
    const float s2 = __expf(t_prime[0]) * LOG2E;
    const float b2 = bias[0] * LOG2E;
    float local = 0.0f;
#pragma unroll
    for (int i = 0; i < 2; ++i)
#pragma unroll
        for (int j = 0; j < 2; ++j)
#pragma unroll
            for (int g2 = 0; g2 < 2; ++g2) {
                float x[8];
#pragma unroll
                for (int e = 0; e < 8; ++e)
                    x[e] = exp2_fast(fmaf(s2, acc[i][j][g2 * 8 + e], b2));
                float p = 1.0f + x[0];
#pragma unroll
                for (int e = 1; e < 8; ++e)
                    p = fmaf(p, x[e], p);      // p *= (1 + x[e])
                local += log2_fast(p);
            }

    // Diagonal blocks: softplus(-z) = softplus(z) - z -> subtract z2.
    if (rowBase == colBase) {
#pragma unroll
        for (int i = 0; i < 2; ++i)
#pragma unroll
            for (int j = 0; j < 2; ++j)
#pragma unroll
                for (int r = 0; r < 16; ++r) {
                    // 32x32 C/D layout (m74/m101): col = lane&31,
                    // row = (r&3) + 8*(r>>2) + 4*(lane>>5)
                    int rowf = (r & 3) + 8 * (r >> 2) + 4 * g;
                    int grow = wv * 64 + i * 32 + rowf;
                    int gcol = wu * 64 + j * 32 + r31;
                    if (grow == gcol) local -= fmaf(s2, acc[i][j][r], b2);
                }
    }

#pragma unroll
    for (int off = 32; off > 0; off >>= 1)
        local += __shfl_xor(local, off, 64);
    if (lane == 0) red[wave] = local;
    __syncthreads();
    if (tid == 0) {
        float total = (red[0] + red[1]) + (red[2] + red[3]);
        atomicAdd(out, total * (LN2 / (float)N));
    }
}

extern "C" void kernel_launch(void* const* d_in, const int* in_sizes, int n_in,
                              void* d_out, int out_size, void* d_ws, size_t ws_size,
                              hipStream_t stream) {
    const float* img = (const float*)d_in[0];
    const float* txt = (const float*)d_in[1];
    const float* tp  = (const float*)d_in[2];
    const float* bs  = (const float*)d_in[3];
    float* out = (float*)d_out;
    int N = in_sizes[0] / D_DIM;    // 16384

    unsigned char* Ab = (unsigned char*)d_ws;       // 4 MB (k-major strips)
    unsigned char* Bb = Ab + (size_t)N * D_DIM;     // +4 MB

    norm_cast_kernel<<<(2 * N) / 64, 256, 0, stream>>>(img, txt, Ab, Bb, out, N);

    int nblk = (N / 128) * (N / 128);               // 16384
    siglip_loss_kernel<<<nblk, 256, 0, stream>>>(Ab, Bb, tp, bs, out, N);
}

// Round 10
// 166.164 us; speedup vs baseline: 1.7678x; 1.7635x over previous
//
#include <hip/hip_runtime.h>

typedef int   i32x4 __attribute__((ext_vector_type(4)));
typedef int   i32x8 __attribute__((ext_vector_type(8)));
typedef float f32x16 __attribute__((ext_vector_type(16)));

#define D_DIM 256
#define LOG2E 1.4426950408889634f
#define LN2   0.6931471805599453f
// Transposed workspace layout: [strip of 128 rows][kc16 0..15][row 0..127][16B]
#define STRIP_BYTES 32768
#define NBLK 16384

#if __has_builtin(__builtin_amdgcn_exp2f)
static __device__ __forceinline__ float exp2_fast(float x) { return __builtin_amdgcn_exp2f(x); }
#else
static __device__ __forceinline__ float exp2_fast(float x) { return __expf(x * LN2); }
#endif
#if __has_builtin(__builtin_amdgcn_logf)
static __device__ __forceinline__ float log2_fast(float x) { return __builtin_amdgcn_logf(x); }
#else
static __device__ __forceinline__ float log2_fast(float x) { return __logf(x) * LOG2E; }
#endif

#if __has_builtin(__builtin_amdgcn_cvt_pk_fp8_f32)
static __device__ __forceinline__ unsigned int pack4_fp8(float a, float b, float c, float d) {
    int v = 0;
    v = __builtin_amdgcn_cvt_pk_fp8_f32(a, b, v, false);
    v = __builtin_amdgcn_cvt_pk_fp8_f32(c, d, v, true);
    return (unsigned int)v;
}
#else
#include <hip/hip_fp8.h>
static __device__ __forceinline__ unsigned char cv1(float x) {
    __hip_fp8_e4m3 f(x);
    union { __hip_fp8_e4m3 f; unsigned char b; } u; u.f = f; return u.b;
}
static __device__ __forceinline__ unsigned int pack4_fp8(float a, float b, float c, float d) {
    return (unsigned int)cv1(a) | ((unsigned int)cv1(b) << 8) |
           ((unsigned int)cv1(c) << 16) | ((unsigned int)cv1(d) << 24);
}
#endif

// K=64 fp8 MFMA (32x32): MX-scaled if available, else 4x K=16 non-scaled.
static __device__ __forceinline__ f32x16 mfma_fp8_32x32_k64(i32x8 a, i32x8 b, f32x16 c) {
#if __has_builtin(__builtin_amdgcn_mfma_scale_f32_32x32x64_f8f6f4)
    return __builtin_amdgcn_mfma_scale_f32_32x32x64_f8f6f4(a, b, c, 0, 0, 0, 127, 0, 127);
#else
    union { i32x8 v; long l[4]; } ua, ub;
    ua.v = a; ub.v = b;
#pragma unroll
    for (int s = 0; s < 4; ++s)
        c = __builtin_amdgcn_mfma_f32_32x32x16_fp8_fp8(ua.l[s], ub.l[s], c, 0, 0, 0);
    return c;
#endif
}

// Kernel 1: L2-normalize fp32 -> fp8 e4m3, writing the k-major strip layout:
// byte(row, k) -> strip(row>>7)*32768 + (k>>4)*2048 + (row&127)*16 + (k&15).
// Block = 256 thr <-> 64 rows; thread (row rl, quarter q) owns 64 floats.
__global__ __launch_bounds__(256) void norm_cast_kernel(
    const float* __restrict__ img, const float* __restrict__ txt,
    unsigned char* __restrict__ Ab, unsigned char* __restrict__ Bb, int N)
{
    const int tid = threadIdx.x;
    const int q   = tid & 3;          // k-quarter (64 floats)
    const int rl  = tid >> 2;         // 0..63
    int gRow = blockIdx.x * 64 + rl;  // 0..2N-1

    const float* src;
    unsigned char* dstB;
    int row;
    if (gRow < N) { row = gRow;     src = img + (size_t)row * D_DIM; dstB = Ab; }
    else          { row = gRow - N; src = txt + (size_t)row * D_DIM; dstB = Bb; }

    float f[64];
    float ss = 0.0f;
    const float4* s4 = (const float4*)(src + q * 64);
#pragma unroll
    for (int i = 0; i < 16; ++i) {
        float4 v = s4[i];
        f[4*i+0] = v.x; f[4*i+1] = v.y; f[4*i+2] = v.z; f[4*i+3] = v.w;
        ss += v.x*v.x + v.y*v.y + v.z*v.z + v.w*v.w;
    }
    // 4 lanes per row (consecutive): xor-1 and xor-2 reduce within the quad.
    ss += __shfl_xor(ss, 1, 64);
    ss += __shfl_xor(ss, 2, 64);
    float inv = 1.0f / fmaxf(sqrtf(ss), 1e-12f);   // F.normalize eps

    unsigned char* dst = dstB + (size_t)(row >> 7) * STRIP_BYTES + (row & 127) * 16;
#pragma unroll
    for (int g = 0; g < 4; ++g) {
        const float* h = f + g * 16;
        uint4 w;
        w.x = pack4_fp8(h[ 0]*inv, h[ 1]*inv, h[ 2]*inv, h[ 3]*inv);
        w.y = pack4_fp8(h[ 4]*inv, h[ 5]*inv, h[ 6]*inv, h[ 7]*inv);
        w.z = pack4_fp8(h[ 8]*inv, h[ 9]*inv, h[10]*inv, h[11]*inv);
        w.w = pack4_fp8(h[12]*inv, h[13]*inv, h[14]*inv, h[15]*inv);
        *(uint4*)(dst + (q * 4 + g) * 2048) = w;   // 16-B aligned, kc = q*4+g
    }
}

// Kernel 2: fp8-MX Gram + softplus-sum + inline diag. Identical to R9 except
// the final reduction: per-block partial is STORED (coalesced, contention-free)
// instead of atomicAdd to out[0] — R8/R9 both plateaued at ~218 us, the
// serialization floor of 16384 same-address device atomics (~13 ns each).
__global__ __launch_bounds__(256, 4) void siglip_loss_kernel(
    const unsigned char* __restrict__ A, const unsigned char* __restrict__ B,
    const float* __restrict__ t_prime, const float* __restrict__ bias,
    float* __restrict__ partials, int N)
{
    __shared__ unsigned char As[2][8192];   // [kc16 0..3][row 0..127][16B]
    __shared__ unsigned char Bs[2][8192];
    __shared__ float red[4];

    const int tid  = threadIdx.x;
    const int wave = tid >> 6;
    const int lane = tid & 63;
    const int r31  = lane & 31;
    const int g    = lane >> 5;       // k-group (2 kc16 chunks of the 4)
    const int wv   = wave >> 1;       // 0..1 row half
    const int wu   = wave & 1;        // 0..1 col half

    // 16x16 supertile swizzle for L2 locality (grid 16384 flat).
    const int bid = blockIdx.x;
    const int st  = bid >> 8;
    const int l2  = bid & 255;
    const int bx  = (st & 7) * 16 + (l2 & 15);
    const int by  = (st >> 3) * 16 + (l2 >> 4);
    const int rowBase = by * 128;
    const int colBase = bx * 128;

    const unsigned char* Astrip = A + (size_t)by * STRIP_BYTES;
    const unsigned char* Bstrip = B + (size_t)bx * STRIP_BYTES;

    // Stage K-chunk c (8 KB per operand = 8 x 1KB loads, 2 per wave each).
    auto stage = [&](int buf, int c) {
        const unsigned char* ga = Astrip + c * 8192;
        const unsigned char* gb = Bstrip + c * 8192;
#pragma unroll
        for (int l = 0; l < 2; ++l) {
            int idx = wave * 2 + l;   // 0..7
            __builtin_amdgcn_global_load_lds(
                (const __attribute__((address_space(1))) unsigned int*)(ga + idx * 1024 + lane * 16),
                (__attribute__((address_space(3))) unsigned int*)&As[buf][idx * 1024],
                16, 0, 0);
            __builtin_amdgcn_global_load_lds(
                (const __attribute__((address_space(1))) unsigned int*)(gb + idx * 1024 + lane * 16),
                (__attribute__((address_space(3))) unsigned int*)&Bs[buf][idx * 1024],
                16, 0, 0);
        }
    };

    stage(0, 0);

    // Fragment LDS offsets: kc_local = 2g (+1 for the second 16B half).
    int a_off[2], b_off[2];
#pragma unroll
    for (int i = 0; i < 2; ++i) a_off[i] = g * 4096 + (wv * 64 + i * 32 + r31) * 16;
#pragma unroll
    for (int j = 0; j < 2; ++j) b_off[j] = g * 4096 + (wu * 64 + j * 32 + r31) * 16;

    f32x16 acc[2][2] = {};
    union F { i32x8 v8; i32x4 v4[2]; };

#pragma unroll 1
    for (int c = 0; c < 4; ++c) {
        __syncthreads();                    // publishes buffer c&1
        if (c < 3) stage((c + 1) & 1, c + 1);

        const unsigned char* as = As[c & 1];
        const unsigned char* bs = Bs[c & 1];
        F a[2], b[2];
#pragma unroll
        for (int i = 0; i < 2; ++i) {
            a[i].v4[0] = *(const i32x4*)&as[a_off[i]];
            a[i].v4[1] = *(const i32x4*)&as[a_off[i] + 2048];
            b[i].v4[0] = *(const i32x4*)&bs[b_off[i]];
            b[i].v4[1] = *(const i32x4*)&bs[b_off[i] + 2048];
        }
#pragma unroll
        for (int i = 0; i < 2; ++i)
#pragma unroll
            for (int j = 0; j < 2; ++j)
                acc[i][j] = mfma_fp8_32x32_k64(a[i].v8, b[j].v8, acc[i][j]);
    }

    // Epilogue: z2 = s2*acc + b2 (log2 domain); log2 of products of 8.
    const float s2 = __expf(t_prime[0]) * LOG2E;
    const float b2 = bias[0] * LOG2E;
    float local = 0.0f;
#pragma unroll
    for (int i = 0; i < 2; ++i)
#pragma unroll
        for (int j = 0; j < 2; ++j)
#pragma unroll
            for (int g2 = 0; g2 < 2; ++g2) {
                float x[8];
#pragma unroll
                for (int e = 0; e < 8; ++e)
                    x[e] = exp2_fast(fmaf(s2, acc[i][j][g2 * 8 + e], b2));
                float p = 1.0f + x[0];
#pragma unroll
                for (int e = 1; e < 8; ++e)
                    p = fmaf(p, x[e], p);      // p *= (1 + x[e])
                local += log2_fast(p);
            }

    // Diagonal blocks: softplus(-z) = softplus(z) - z -> subtract z2.
    if (rowBase == colBase) {
#pragma unroll
        for (int i = 0; i < 2; ++i)
#pragma unroll
            for (int j = 0; j < 2; ++j)
#pragma unroll
                for (int r = 0; r < 16; ++r) {
                    // 32x32 C/D layout (m74/m101): col = lane&31,
                    // row = (r&3) + 8*(r>>2) + 4*(lane>>5)
                    int rowf = (r & 3) + 8 * (r >> 2) + 4 * g;
                    int grow = wv * 64 + i * 32 + rowf;
                    int gcol = wu * 64 + j * 32 + r31;
                    if (grow == gcol) local -= fmaf(s2, acc[i][j][r], b2);
                }
    }

#pragma unroll
    for (int off = 32; off > 0; off >>= 1)
        local += __shfl_xor(local, off, 64);
    if (lane == 0) red[wave] = local;
    __syncthreads();
    if (tid == 0)
        partials[bid] = (red[0] + red[1]) + (red[2] + red[3]);   // plain store
}

// Kernel 3: reduce 16384 per-block partials -> out[0]. One block, ~3 us.
__global__ __launch_bounds__(1024) void reduce_kernel(
    const float* __restrict__ partials, float* __restrict__ out, int N)
{
    __shared__ float red[16];
    const int tid  = threadIdx.x;
    const int wave = tid >> 6;
    const int lane = tid & 63;
    float s = 0.0f;
#pragma unroll 4
    for (int i = tid; i < NBLK; i += 1024)
        s += partials[i];
#pragma unroll
    for (int off = 32; off > 0; off >>= 1)
        s += __shfl_xor(s, off, 64);
    if (lane == 0) red[wave] = s;
    __syncthreads();
    if (tid == 0) {
        float t = 0.0f;
#pragma unroll
        for (int w = 0; w < 16; ++w) t += red[w];
        out[0] = t * (LN2 / (float)N);
    }
}

extern "C" void kernel_launch(void* const* d_in, const int* in_sizes, int n_in,
                              void* d_out, int out_size, void* d_ws, size_t ws_size,
                              hipStream_t stream) {
    const float* img = (const float*)d_in[0];
    const float* txt = (const float*)d_in[1];
    const float* tp  = (const float*)d_in[2];
    const float* bs  = (const float*)d_in[3];
    float* out = (float*)d_out;
    int N = in_sizes[0] / D_DIM;    // 16384

    unsigned char* Ab = (unsigned char*)d_ws;       // 4 MB (k-major strips)
    unsigned char* Bb = Ab + (size_t)N * D_DIM;     // +4 MB
    float* partials   = (float*)(Bb + (size_t)N * D_DIM);   // 64 KB

    norm_cast_kernel<<<(2 * N) / 64, 256, 0, stream>>>(img, txt, Ab, Bb, N);
    siglip_loss_kernel<<<NBLK, 256, 0, stream>>>(Ab, Bb, tp, bs, partials, N);
    reduce_kernel<<<1, 1024, 0, stream>>>(partials, out, N);
}